// Round 4
// baseline (10625.278 us; speedup 1.0000x reference)
//
#include <hip/hip_runtime.h>
#include <cstdint>
#include <cstddef>

// ---------------------------------------------------------------------------
// RNN_42537356100303: 3-layer tanh RNN (B=128,T=1024,F=24,H=512) + MLP head.
// Phase plan (all on one in-place f16 buffer P[B*T, 512] in ws):
//   k_cvt   : fp32 weights -> f16 (W_hh0..2, W_ih1..2), bias_l = b_ih+b_hh
//   k_xp0   : P = x @ W_ih0^T + bias0            (VALU, K=24)
//   k_scan  : P[b,t,:] = h_t  in-place. 2-way k-split: thread (half,po) owns
//             outputs {2po,2po+1} x k-half; W fully register-resident;
//             h broadcast from LDS (b128), partials combined via LDS pbuf.
//   k_proj  : P = P @ W_ih^T + bias  (in-place row-block MFMA f16 GEMM)
//   k_head  : out = silu(last @ W1^T + b1) @ W2^T + b2
// ---------------------------------------------------------------------------

typedef _Float16 half_t;
typedef __attribute__((ext_vector_type(2))) _Float16 half2_t;
typedef __attribute__((ext_vector_type(8))) _Float16 frag8;
typedef __attribute__((ext_vector_type(4))) float    frag4;

union U32H2 { unsigned u; half2_t h2; };

__device__ __forceinline__ float dot2(unsigned a, unsigned b, float c) {
#if __has_builtin(__builtin_amdgcn_fdot2)
    U32H2 ua; ua.u = a; U32H2 ub; ub.u = b;
    return __builtin_amdgcn_fdot2(ua.h2, ub.h2, c, false);
#else
    U32H2 ua; ua.u = a; U32H2 ub; ub.u = b;
    c += (float)ua.h2.x * (float)ub.h2.x;
    c += (float)ua.h2.y * (float)ub.h2.y;
    return c;
#endif
}

__device__ __forceinline__ float fast_tanh(float x) {
    float ax = __builtin_fabsf(x);
    float e  = __expf(-2.f * ax);          // v_exp_f32 path
    float r  = (1.f - e) / (1.f + e);
    return __builtin_copysignf(r, x);
}

#define WN (512 * 512)

// -------------------------------------------------------------- k_cvt ------
__global__ __launch_bounds__(256) void k_cvt(
    const float* whh0, const float* whh1, const float* whh2,
    const float* wih1, const float* wih2,
    const float* bi0, const float* bh0, const float* bi1, const float* bh1,
    const float* bi2, const float* bh2,
    half_t* w16, float* bias)
{
    int idx = blockIdx.x * 256 + threadIdx.x;
    if (idx < 5 * WN) {
        int seg = idx / WN, off = idx % WN;
        const float* s = seg == 0 ? whh0 : seg == 1 ? whh1 : seg == 2 ? whh2
                       : seg == 3 ? wih1 : wih2;
        w16[idx] = (half_t)s[off];
    } else {
        int j = idx - 5 * WN;
        if (j < 3 * 512) {
            int l = j >> 9, o = j & 511;
            const float* a = l == 0 ? bi0 : l == 1 ? bi1 : bi2;
            const float* c = l == 0 ? bh0 : l == 1 ? bh1 : bh2;
            bias[j] = a[o] + c[o];
        }
    }
}

// -------------------------------------------------------------- k_xp0 ------
// wl stride padded 24 -> 25: the o-varying read (lane stride 192 floats, all
// same bank, 8-way) becomes 2-way (benign).
__global__ __launch_bounds__(256) void k_xp0(
    const float* __restrict__ x, const float* __restrict__ wih0,
    const float* __restrict__ bias0, half_t* __restrict__ P)
{
    __shared__ float wl[512 * 25];
    __shared__ float xl[32 * 25];
    int tid = threadIdx.x;
    int r0  = blockIdx.x * 32;
    for (int i = tid; i < 512 * 24; i += 256) {
        int o = i / 24, f = i - o * 24;
        wl[o * 25 + f] = wih0[i];
    }
    for (int i = tid; i < 32 * 24; i += 256) {
        int r = i / 24, f = i - r * 24;
        xl[r * 25 + f] = x[(size_t)(r0 + r) * 24 + f];
    }
    __syncthreads();
    int r = tid >> 3, c = tid & 7;
    float xr[24];
#pragma unroll
    for (int f = 0; f < 24; f++) xr[f] = xl[r * 25 + f];
    size_t orow = (size_t)(r0 + r) * 512;
    for (int og = 0; og < 8; og++) {
        half_t hv[8];
#pragma unroll
        for (int oj = 0; oj < 8; oj++) {
            int o = og * 64 + c * 8 + oj;
            float acc = bias0[o];
#pragma unroll
            for (int f = 0; f < 24; f++) acc = fmaf(xr[f], wl[o * 25 + f], acc);
            hv[oj] = (half_t)acc;
        }
        *(uint4*)(P + orow + og * 64 + c * 8) = *(const uint4*)hv;
    }
}

// -------------------------------------------------------------- k_scan -----
// One WG (512 thr) per batch element. 2-way k-split:
//   half = tid>>8 selects k in [half*256, half*256+256)
//   po   = tid&255 -> thread owns outputs 2po, 2po+1 (W rows in 256 regs)
// Per step: 32 broadcast ds_read_b128 of the h-half, 256 v_dot2, partial
// exchange via pbuf (b64), both halves combine+tanh; half0 writes hbuf,
// half1 writes P (global). 2 barriers/step, zero bank conflicts by design.
__global__ __launch_bounds__(512, 2) void k_scan(
    half_t* __restrict__ P, const half_t* __restrict__ whh)
{
    __shared__ unsigned hbuf[2][256];   // packed f16 pairs of h
    __shared__ float2   pbuf[2][256];   // partial sums per output pair

    int tid  = threadIdx.x;
    int half = tid >> 8;
    int po   = tid & 255;
    int b    = blockIdx.x;

    const uint4* w0p = (const uint4*)(whh + (size_t)(2 * po)     * 512 + half * 256);
    const uint4* w1p = (const uint4*)(whh + (size_t)(2 * po + 1) * 512 + half * 256);
    uint4 w0[32], w1[32];
#pragma unroll
    for (int g = 0; g < 32; g++) { w0[g] = w0p[g]; w1[g] = w1p[g]; }

    if (half == 0) { hbuf[0][po] = 0u; hbuf[1][po] = 0u; }
    __syncthreads();

    unsigned* Pb32 = (unsigned*)(P + (size_t)b * 1024 * 512);
    int cur = 0;
    for (int t = 0; t < 1024; t++) {
        unsigned xpu = Pb32[t * 256 + po];          // xp pair (global, L3-hot)
        const uint4* h4 = (const uint4*)hbuf[cur] + half * 32;
        float a0 = 0.f, a1 = 0.f, a2 = 0.f, a3 = 0.f;
        float c0 = 0.f, c1 = 0.f, c2 = 0.f, c3 = 0.f;
#pragma unroll
        for (int g = 0; g < 32; g++) {
            uint4 hv = h4[g];                       // wave-uniform broadcast
            uint4 wv0 = w0[g], wv1 = w1[g];
            a0 = dot2(wv0.x, hv.x, a0); a1 = dot2(wv0.y, hv.y, a1);
            a2 = dot2(wv0.z, hv.z, a2); a3 = dot2(wv0.w, hv.w, a3);
            c0 = dot2(wv1.x, hv.x, c0); c1 = dot2(wv1.y, hv.y, c1);
            c2 = dot2(wv1.z, hv.z, c2); c3 = dot2(wv1.w, hv.w, c3);
        }
        float p0 = (a0 + a1) + (a2 + a3);
        float p1 = (c0 + c1) + (c2 + c3);
        pbuf[half][po] = make_float2(p0, p1);
        __syncthreads();                            // A: partials visible
        float2 q = pbuf[half ^ 1][po];
        U32H2 xu; xu.u = xpu;
        float s0 = p0 + q.x + (float)xu.h2.x;
        float s1 = p1 + q.y + (float)xu.h2.y;
        U32H2 hu;
        hu.h2.x = (half_t)fast_tanh(s0);
        hu.h2.y = (half_t)fast_tanh(s1);
        if (half == 0) hbuf[cur ^ 1][po] = hu.u;    // next-step h
        else           Pb32[t * 256 + po] = hu.u;   // in-place over xp
        __syncthreads();                            // B: h ready
        cur ^= 1;
    }
}

// -------------------------------------------------------------- k_proj -----
// In-place row-block GEMM: rows [r0, r0+64) of P times W^T (W = [512 o][512 k]
// f16), + bias, overwrite. MFMA f32_16x16x32_f16.
__global__ __launch_bounds__(256, 2) void k_proj(
    half_t* __restrict__ P, const half_t* __restrict__ w16,
    const float* __restrict__ bias)
{
    extern __shared__ char smem[];
    half_t* A = (half_t*)smem;                  // 64 rows x stride 520 (65 KB)
    const int AS = 520;
    int tid = threadIdx.x;
    size_t r0 = (size_t)blockIdx.x * 64;

    const uint4* Pg = (const uint4*)(P + r0 * 512);
    for (int u = tid; u < 4096; u += 256) {     // 64 rows x 64 uint4
        uint4 v = Pg[u];
        int row = u >> 6, col = u & 63;
        *(uint4*)(A + row * AS + col * 8) = v;
    }
    __syncthreads();

    int wave = tid >> 6, lane = tid & 63;
    int lm = lane & 15, lq = lane >> 4;

    frag4 acc[4][8];
#pragma unroll
    for (int mt = 0; mt < 4; mt++)
#pragma unroll
        for (int nt = 0; nt < 8; nt++) acc[mt][nt] = (frag4){0.f, 0.f, 0.f, 0.f};

    for (int kb = 0; kb < 16; kb++) {
        int k0 = kb * 32 + lq * 8;
        frag8 af[4];
#pragma unroll
        for (int mt = 0; mt < 4; mt++)
            af[mt] = *(const frag8*)(A + (mt * 16 + lm) * AS + k0);
        frag8 bf[8];
#pragma unroll
        for (int nt = 0; nt < 8; nt++) {
            int n = wave * 128 + nt * 16 + lm;
            bf[nt] = *(const frag8*)(w16 + (size_t)n * 512 + k0);
        }
#pragma unroll
        for (int mt = 0; mt < 4; mt++)
#pragma unroll
            for (int nt = 0; nt < 8; nt++)
                acc[mt][nt] = __builtin_amdgcn_mfma_f32_16x16x32_f16(
                    af[mt], bf[nt], acc[mt][nt], 0, 0, 0);
    }

#pragma unroll
    for (int mt = 0; mt < 4; mt++) {
        int row = mt * 16 + lq * 4;
#pragma unroll
        for (int nt = 0; nt < 8; nt++) {
            int oc = wave * 128 + nt * 16 + lm;
            float bo = bias[oc];
#pragma unroll
            for (int i = 0; i < 4; i++) {
                float v = acc[mt][nt][i] + bo;
                P[(r0 + row + i) * 512 + oc] = (half_t)v;
            }
        }
    }
}

// -------------------------------------------------------------- k_head -----
__global__ __launch_bounds__(256) void k_head(
    const half_t* __restrict__ P, const float* __restrict__ W1,
    const float* __restrict__ b1, const float* __restrict__ W2,
    const float* __restrict__ b2, float* __restrict__ out)
{
    __shared__ float lastv[512];
    __shared__ float zl[1024];
    __shared__ float red[8][33];
    int tid = threadIdx.x, b = blockIdx.x;
    const half_t* lr = P + ((size_t)b * 1024 + 1023) * 512;
    lastv[tid]       = (float)lr[tid];
    lastv[tid + 256] = (float)lr[tid + 256];
    __syncthreads();
#pragma unroll
    for (int i = 0; i < 4; i++) {
        int m = tid + 256 * i;
        const float* wr = W1 + (size_t)m * 512;
        float acc = b1[m];
        for (int k = 0; k < 512; k += 4) {
            float4 wv = *(const float4*)(wr + k);
            acc = fmaf(wv.x, lastv[k],     acc);
            acc = fmaf(wv.y, lastv[k + 1], acc);
            acc = fmaf(wv.z, lastv[k + 2], acc);
            acc = fmaf(wv.w, lastv[k + 3], acc);
        }
        zl[m] = acc / (1.f + __expf(-acc));         // silu
    }
    __syncthreads();
    int c = tid & 7, mc = tid >> 3;                 // 8 outputs x 32 m-chunks
    float p = 0.f;
#pragma unroll
    for (int j = 0; j < 32; j++) {
        int m = mc * 32 + j;
        p = fmaf(zl[m], W2[c * 1024 + m], p);
    }
    red[c][mc] = p;
    __syncthreads();
    if (tid < 8) {
        float s = b2[tid];
#pragma unroll
        for (int j = 0; j < 32; j++) s += red[tid][j];
        out[b * 8 + tid] = s;
    }
}

// ---------------------------------------------------------------------------
extern "C" void kernel_launch(void* const* d_in, const int* in_sizes, int n_in,
                              void* d_out, int out_size, void* d_ws, size_t ws_size,
                              hipStream_t stream)
{
    const float* x    = (const float*)d_in[0];
    const float* wih0 = (const float*)d_in[1];
    const float* whh0 = (const float*)d_in[2];
    const float* bi0  = (const float*)d_in[3];
    const float* bh0  = (const float*)d_in[4];
    const float* wih1 = (const float*)d_in[5];
    const float* whh1 = (const float*)d_in[6];
    const float* bi1  = (const float*)d_in[7];
    const float* bh1  = (const float*)d_in[8];
    const float* wih2 = (const float*)d_in[9];
    const float* whh2 = (const float*)d_in[10];
    const float* bi2  = (const float*)d_in[11];
    const float* bh2  = (const float*)d_in[12];
    const float* W1   = (const float*)d_in[13];
    const float* b1   = (const float*)d_in[14];
    const float* W2   = (const float*)d_in[15];
    const float* b2   = (const float*)d_in[16];
    float* out = (float*)d_out;

    char* ws = (char*)d_ws;
    half_t* P    = (half_t*)ws;                               // 134,217,728 B
    half_t* W16  = (half_t*)(ws + 134217728);                 //   2,621,440 B
    float*  bias = (float*)(ws + 134217728 + 2621440);        //       6,144 B

    // dynamic-LDS opt-in (>64 KB); idempotent, not a stream op
    hipFuncSetAttribute((const void*)k_proj,
                        hipFuncAttributeMaxDynamicSharedMemorySize, 66560);

    k_cvt<<<5126, 256, 0, stream>>>(whh0, whh1, whh2, wih1, wih2,
                                    bi0, bh0, bi1, bh1, bi2, bh2, W16, bias);
    k_xp0<<<4096, 256, 0, stream>>>(x, wih0, bias, P);
    k_scan<<<128, 512, 0, stream>>>(P, W16 + 0 * WN);
    k_proj<<<2048, 256, 66560, stream>>>(P, W16 + 3 * WN, bias + 512);
    k_scan<<<128, 512, 0, stream>>>(P, W16 + 1 * WN);
    k_proj<<<2048, 256, 66560, stream>>>(P, W16 + 4 * WN, bias + 1024);
    k_scan<<<128, 512, 0, stream>>>(P, W16 + 2 * WN);
    k_head<<<128, 256, 0, stream>>>(P, W1, b1, W2, b2, out);
}

// Round 5
// 6369.487 us; speedup vs baseline: 1.6682x; 1.6682x over previous
//
#include <hip/hip_runtime.h>
#include <cstdint>
#include <cstddef>

// ---------------------------------------------------------------------------
// RNN_42537356100303: 3-layer tanh RNN (B=128,T=1024,F=24,H=512) + MLP head.
// Phase plan (all on one in-place f16 buffer P[B*T, 512] in ws):
//   k_cvt   : fp32 weights -> f16 (W_hh0..2, W_ih1..2), bias_l = b_ih+b_hh
//   k_xp0   : P = x @ W_ih0^T + bias0            (VALU, K=24)
//   k_scan  : P[b,t,:] = h_t in-place. MFMA matvec: W as A-fragments resident
//             in AGPRs (56/wave) + LDS (8/wave); h broadcast as B-fragments
//             (all 16 cols = same h => every col of D is valid y).
//   k_proj  : P = P @ W_ih^T + bias  (in-place row-block MFMA f16 GEMM)
//   k_head  : out = silu(last @ W1^T + b1) @ W2^T + b2
// ---------------------------------------------------------------------------

typedef _Float16 half_t;
typedef __attribute__((ext_vector_type(2))) _Float16 half2_t;
typedef __attribute__((ext_vector_type(8))) _Float16 frag8;
typedef __attribute__((ext_vector_type(4))) float    frag4;

union U32H2 { unsigned u; half2_t h2; };

__device__ __forceinline__ float fast_tanh(float x) {
    float ax = __builtin_fabsf(x);
    float e  = __expf(-2.f * ax);          // v_exp_f32 path
    float r  = (1.f - e) / (1.f + e);
    return __builtin_copysignf(r, x);
}

#define WN (512 * 512)

// -------------------------------------------------------------- k_cvt ------
__global__ __launch_bounds__(256) void k_cvt(
    const float* whh0, const float* whh1, const float* whh2,
    const float* wih1, const float* wih2,
    const float* bi0, const float* bh0, const float* bi1, const float* bh1,
    const float* bi2, const float* bh2,
    half_t* w16, float* bias)
{
    int idx = blockIdx.x * 256 + threadIdx.x;
    if (idx < 5 * WN) {
        int seg = idx / WN, off = idx % WN;
        const float* s = seg == 0 ? whh0 : seg == 1 ? whh1 : seg == 2 ? whh2
                       : seg == 3 ? wih1 : wih2;
        w16[idx] = (half_t)s[off];
    } else {
        int j = idx - 5 * WN;
        if (j < 3 * 512) {
            int l = j >> 9, o = j & 511;
            const float* a = l == 0 ? bi0 : l == 1 ? bi1 : bi2;
            const float* c = l == 0 ? bh0 : l == 1 ? bh1 : bh2;
            bias[j] = a[o] + c[o];
        }
    }
}

// -------------------------------------------------------------- k_xp0 ------
// wl stride padded 24 -> 25 (8-way bank conflict -> benign 2-way).
__global__ __launch_bounds__(256) void k_xp0(
    const float* __restrict__ x, const float* __restrict__ wih0,
    const float* __restrict__ bias0, half_t* __restrict__ P)
{
    __shared__ float wl[512 * 25];
    __shared__ float xl[32 * 25];
    int tid = threadIdx.x;
    int r0  = blockIdx.x * 32;
    for (int i = tid; i < 512 * 24; i += 256) {
        int o = i / 24, f = i - o * 24;
        wl[o * 25 + f] = wih0[i];
    }
    for (int i = tid; i < 32 * 24; i += 256) {
        int r = i / 24, f = i - r * 24;
        xl[r * 25 + f] = x[(size_t)(r0 + r) * 24 + f];
    }
    __syncthreads();
    int r = tid >> 3, c = tid & 7;
    float xr[24];
#pragma unroll
    for (int f = 0; f < 24; f++) xr[f] = xl[r * 25 + f];
    size_t orow = (size_t)(r0 + r) * 512;
    for (int og = 0; og < 8; og++) {
        half_t hv[8];
#pragma unroll
        for (int oj = 0; oj < 8; oj++) {
            int o = og * 64 + c * 8 + oj;
            float acc = bias0[o];
#pragma unroll
            for (int f = 0; f < 24; f++) acc = fmaf(xr[f], wl[o * 25 + f], acc);
            hv[oj] = (half_t)acc;
        }
        *(uint4*)(P + orow + og * 64 + c * 8) = *(const uint4*)hv;
    }
}

// -------------------------------------------------------------- k_scan -----
// One WG (512 thr, 8 waves) per batch element. Wave w owns outputs
// [w*64, w*64+64) as 4 m-tiles of mfma_f32_16x16x32_f16.
// A-frag (W): lane holds W[out = w*64+mt*16+(lane&15)][kb*32+quad*8+j].
//   kb 0..13 resident in registers (56 frag8 = 224 regs, AGPR-friendly);
//   kb 14..15 staged in LDS (8 frag8/lane).
// B-frag (h): all lanes load the SAME h-uint4 per (kb,quad) -> quad-broadcast
//   ds_read_b128; every column n of D equals y = W.h (B cols identical).
// Epilogue on col<4 lanes: y rows quad*4..+3 of tile mt=col; add xp, tanh,
// write hbuf (next h) + P (in-place). 1 barrier/step.
__global__ __launch_bounds__(512, 2) void k_scan(
    half_t* __restrict__ P, const half_t* __restrict__ whh)
{
    extern __shared__ char smem[];
    frag8*    wlds = (frag8*)smem;                 // [8 waves][8 tiles][64 ln] 64 KB
    unsigned* hbuf = (unsigned*)(smem + 65536);    // [2][256] u32 (packed h)   2 KB

    int tid  = threadIdx.x;
    int w    = tid >> 6, lane = tid & 63;
    int col  = lane & 15, quad = lane >> 4;
    int b    = blockIdx.x;

    // ---- setup: W fragments (constant over all 1024 steps) ----
    frag8 areg[4][14];
#pragma unroll
    for (int mt = 0; mt < 4; mt++) {
        int out = w * 64 + mt * 16 + col;
        const half_t* wr = whh + (size_t)out * 512 + quad * 8;
#pragma unroll
        for (int kb = 0; kb < 14; kb++)
            areg[mt][kb] = *(const frag8*)(wr + kb * 32);
#pragma unroll
        for (int i = 0; i < 2; i++)
            wlds[(w * 8 + i * 4 + mt) * 64 + lane] = *(const frag8*)(wr + (14 + i) * 32);
    }
    if (tid < 256) { hbuf[tid] = 0u; hbuf[256 + tid] = 0u; }   // h0 = 0
    __syncthreads();

    half_t* Pb = P + (size_t)b * 1024 * 512;
    int  out0 = w * 64 + col * 16 + quad * 4;      // 4 outputs for col<4 lanes
    bool act  = (col < 4);
    uint2 xq = make_uint2(0u, 0u);
    if (act) xq = *(const uint2*)(Pb + out0);      // xp(t=0) prefetch
    int cur = 0;
    for (int t = 0; t < 1024; t++) {
        const uint4* hb4 = (const uint4*)(hbuf + cur * 256);
        frag4 acc[4];
#pragma unroll
        for (int mt = 0; mt < 4; mt++) acc[mt] = (frag4){0.f, 0.f, 0.f, 0.f};
#pragma unroll
        for (int kb = 0; kb < 14; kb++) {
            uint4 bu = hb4[kb * 4 + quad];         // quad-broadcast b128
            frag8 bf = *(const frag8*)&bu;
#pragma unroll
            for (int mt = 0; mt < 4; mt++)
                acc[mt] = __builtin_amdgcn_mfma_f32_16x16x32_f16(
                    areg[mt][kb], bf, acc[mt], 0, 0, 0);
        }
#pragma unroll
        for (int i = 0; i < 2; i++) {
            uint4 bu = hb4[(14 + i) * 4 + quad];
            frag8 bf = *(const frag8*)&bu;
#pragma unroll
            for (int mt = 0; mt < 4; mt++) {
                frag8 a = wlds[(w * 8 + i * 4 + mt) * 64 + lane];
                acc[mt] = __builtin_amdgcn_mfma_f32_16x16x32_f16(
                    a, bf, acc[mt], 0, 0, 0);
            }
        }
        if (act) {
            int tn = (t + 1 < 1024) ? t + 1 : 1023;
            uint2 xn = *(const uint2*)(Pb + (size_t)tn * 512 + out0);
            float y0 = 0.f, y1 = 0.f, y2 = 0.f, y3 = 0.f;
#pragma unroll
            for (int mt = 0; mt < 4; mt++)
                if (col == mt) { y0 = acc[mt][0]; y1 = acc[mt][1];
                                 y2 = acc[mt][2]; y3 = acc[mt][3]; }
            U32H2 lo, hi; lo.u = xq.x; hi.u = xq.y;
            U32H2 ho, h1;
            ho.h2.x = (half_t)fast_tanh(y0 + (float)lo.h2.x);
            ho.h2.y = (half_t)fast_tanh(y1 + (float)lo.h2.y);
            h1.h2.x = (half_t)fast_tanh(y2 + (float)hi.h2.x);
            h1.h2.y = (half_t)fast_tanh(y3 + (float)hi.h2.y);
            uint2 hv = make_uint2(ho.u, h1.u);
            *(uint2*)&hbuf[(cur ^ 1) * 256 + (out0 >> 1)] = hv;  // next h
            *(uint2*)(Pb + (size_t)t * 512 + out0) = hv;         // in-place
            xq = xn;
        }
        __syncthreads();
        cur ^= 1;
    }
}

// -------------------------------------------------------------- k_proj -----
// In-place row-block GEMM: rows [r0, r0+64) of P times W^T (W = [512 o][512 k]
// f16), + bias, overwrite. MFMA f32_16x16x32_f16.
__global__ __launch_bounds__(256, 2) void k_proj(
    half_t* __restrict__ P, const half_t* __restrict__ w16,
    const float* __restrict__ bias)
{
    extern __shared__ char smem[];
    half_t* A = (half_t*)smem;                  // 64 rows x stride 520 (65 KB)
    const int AS = 520;
    int tid = threadIdx.x;
    size_t r0 = (size_t)blockIdx.x * 64;

    const uint4* Pg = (const uint4*)(P + r0 * 512);
    for (int u = tid; u < 4096; u += 256) {     // 64 rows x 64 uint4
        uint4 v = Pg[u];
        int row = u >> 6, c = u & 63;
        *(uint4*)(A + row * AS + c * 8) = v;
    }
    __syncthreads();

    int wave = tid >> 6, lane = tid & 63;
    int lm = lane & 15, lq = lane >> 4;

    frag4 acc[4][8];
#pragma unroll
    for (int mt = 0; mt < 4; mt++)
#pragma unroll
        for (int nt = 0; nt < 8; nt++) acc[mt][nt] = (frag4){0.f, 0.f, 0.f, 0.f};

    for (int kb = 0; kb < 16; kb++) {
        int k0 = kb * 32 + lq * 8;
        frag8 af[4];
#pragma unroll
        for (int mt = 0; mt < 4; mt++)
            af[mt] = *(const frag8*)(A + (mt * 16 + lm) * AS + k0);
        frag8 bf[8];
#pragma unroll
        for (int nt = 0; nt < 8; nt++) {
            int n = wave * 128 + nt * 16 + lm;
            bf[nt] = *(const frag8*)(w16 + (size_t)n * 512 + k0);
        }
#pragma unroll
        for (int mt = 0; mt < 4; mt++)
#pragma unroll
            for (int nt = 0; nt < 8; nt++)
                acc[mt][nt] = __builtin_amdgcn_mfma_f32_16x16x32_f16(
                    af[mt], bf[nt], acc[mt][nt], 0, 0, 0);
    }

#pragma unroll
    for (int mt = 0; mt < 4; mt++) {
        int row = mt * 16 + lq * 4;
#pragma unroll
        for (int nt = 0; nt < 8; nt++) {
            int oc = wave * 128 + nt * 16 + lm;
            float bo = bias[oc];
#pragma unroll
            for (int i = 0; i < 4; i++) {
                float v = acc[mt][nt][i] + bo;
                P[(r0 + row + i) * 512 + oc] = (half_t)v;
            }
        }
    }
}

// -------------------------------------------------------------- k_head -----
__global__ __launch_bounds__(256) void k_head(
    const half_t* __restrict__ P, const float* __restrict__ W1,
    const float* __restrict__ b1, const float* __restrict__ W2,
    const float* __restrict__ b2, float* __restrict__ out)
{
    __shared__ float lastv[512];
    __shared__ float zl[1024];
    __shared__ float red[8][33];
    int tid = threadIdx.x, b = blockIdx.x;
    const half_t* lr = P + ((size_t)b * 1024 + 1023) * 512;
    lastv[tid]       = (float)lr[tid];
    lastv[tid + 256] = (float)lr[tid + 256];
    __syncthreads();
#pragma unroll
    for (int i = 0; i < 4; i++) {
        int m = tid + 256 * i;
        const float* wr = W1 + (size_t)m * 512;
        float acc = b1[m];
        for (int k = 0; k < 512; k += 4) {
            float4 wv = *(const float4*)(wr + k);
            acc = fmaf(wv.x, lastv[k],     acc);
            acc = fmaf(wv.y, lastv[k + 1], acc);
            acc = fmaf(wv.z, lastv[k + 2], acc);
            acc = fmaf(wv.w, lastv[k + 3], acc);
        }
        zl[m] = acc / (1.f + __expf(-acc));         // silu
    }
    __syncthreads();
    int c = tid & 7, mc = tid >> 3;                 // 8 outputs x 32 m-chunks
    float p = 0.f;
#pragma unroll
    for (int j = 0; j < 32; j++) {
        int m = mc * 32 + j;
        p = fmaf(zl[m], W2[c * 1024 + m], p);
    }
    red[c][mc] = p;
    __syncthreads();
    if (tid < 8) {
        float s = b2[tid];
#pragma unroll
        for (int j = 0; j < 32; j++) s += red[tid][j];
        out[b * 8 + tid] = s;
    }
}

// ---------------------------------------------------------------------------
extern "C" void kernel_launch(void* const* d_in, const int* in_sizes, int n_in,
                              void* d_out, int out_size, void* d_ws, size_t ws_size,
                              hipStream_t stream)
{
    const float* x    = (const float*)d_in[0];
    const float* wih0 = (const float*)d_in[1];
    const float* whh0 = (const float*)d_in[2];
    const float* bi0  = (const float*)d_in[3];
    const float* bh0  = (const float*)d_in[4];
    const float* wih1 = (const float*)d_in[5];
    const float* whh1 = (const float*)d_in[6];
    const float* bi1  = (const float*)d_in[7];
    const float* bh1  = (const float*)d_in[8];
    const float* wih2 = (const float*)d_in[9];
    const float* whh2 = (const float*)d_in[10];
    const float* bi2  = (const float*)d_in[11];
    const float* bh2  = (const float*)d_in[12];
    const float* W1   = (const float*)d_in[13];
    const float* b1   = (const float*)d_in[14];
    const float* W2   = (const float*)d_in[15];
    const float* b2   = (const float*)d_in[16];
    float* out = (float*)d_out;

    char* ws = (char*)d_ws;
    half_t* P    = (half_t*)ws;                               // 134,217,728 B
    half_t* W16  = (half_t*)(ws + 134217728);                 //   2,621,440 B
    float*  bias = (float*)(ws + 134217728 + 2621440);        //       6,144 B

    // dynamic-LDS opt-in (>64 KB); idempotent, not a stream op
    hipFuncSetAttribute((const void*)k_scan,
                        hipFuncAttributeMaxDynamicSharedMemorySize, 67584);
    hipFuncSetAttribute((const void*)k_proj,
                        hipFuncAttributeMaxDynamicSharedMemorySize, 66560);

    k_cvt<<<5126, 256, 0, stream>>>(whh0, whh1, whh2, wih1, wih2,
                                    bi0, bh0, bi1, bh1, bi2, bh2, W16, bias);
    k_xp0<<<4096, 256, 0, stream>>>(x, wih0, bias, P);
    k_scan<<<128, 512, 67584, stream>>>(P, W16 + 0 * WN);
    k_proj<<<2048, 256, 66560, stream>>>(P, W16 + 3 * WN, bias + 512);
    k_scan<<<128, 512, 67584, stream>>>(P, W16 + 1 * WN);
    k_proj<<<2048, 256, 66560, stream>>>(P, W16 + 4 * WN, bias + 1024);
    k_scan<<<128, 512, 67584, stream>>>(P, W16 + 2 * WN);
    k_head<<<128, 256, 0, stream>>>(P, W1, b1, W2, b2, out);
}